// Round 8
// baseline (591.824 us; speedup 1.0000x reference)
//
#include <hip/hip_runtime.h>
#include <stdint.h>

#define B_ 2
#define N_ 4096
#define D_ 256
#define H_ 8
#define DH_ 64
#define INNER_ 512
#define NBH 16
#define PAD 72
#define SPLIT 4
#define TSTR 1040   // LDS row stride for t chunk: 16B-aligned, bank-spreading

typedef unsigned short ushort_t;
typedef __attribute__((ext_vector_type(8))) short short8;
typedef __attribute__((ext_vector_type(4))) float float4v;
typedef __attribute__((ext_vector_type(4))) unsigned short ushort4v;
typedef __attribute__((ext_vector_type(4))) unsigned int uint4v;

__device__ __forceinline__ ushort_t f2bf(float f) {
    union { float f; unsigned int u; } v; v.f = f;
    unsigned int r = v.u + 0x7FFFu + ((v.u >> 16) & 1u);
    return (ushort_t)(r >> 16);
}
__device__ __forceinline__ float bf2f(ushort_t u) {
    union { unsigned int u; float f; } v; v.u = ((unsigned int)u) << 16;
    return v.f;
}
// full signed fp8 e4m3 encode with subnormal + clamp handling (for t values)
__device__ __forceinline__ unsigned char f2fp8s(float f) {
    union { float f; unsigned int u; } v; v.f = f;
    unsigned int s = (v.u >> 24) & 0x80u;
    v.u &= 0x7FFFFFFFu;
    float a = v.f;
    if (a >= 448.f) return (unsigned char)(s | 0x7E);
    if (a < 0.015625f) {
        int m = (int)(a * 512.f + 0.5f);
        return (unsigned char)(s | (unsigned)m);
    }
    unsigned int u = v.u + 0x7FFFFu + ((v.u >> 20) & 1u);
    return (unsigned char)(s | (((u >> 20) & 0x7FF) - 960));
}

// ---------------- prep: bf16 conversions + weight transposes ----------------
__global__ __launch_bounds__(256) void prep_kernel(
    const float* __restrict__ x, const float* __restrict__ Wq,
    const float* __restrict__ Wk, const float* __restrict__ Wv,
    const float* __restrict__ Wo,
    ushort_t* __restrict__ xb, ushort_t* __restrict__ WqkvT,
    ushort_t* __restrict__ WoT) {
    int idx = blockIdx.x * 256 + threadIdx.x;
    const int total_x = B_ * N_ * D_;
    const int total_wqkv = 3 * INNER_ * D_;
    const int total_wo = D_ * INNER_;
    if (idx < total_x) { xb[idx] = f2bf(x[idx]); return; }
    idx -= total_x;
    if (idx < total_wqkv) {
        int n = idx >> 8, k = idx & 255;
        int which = n >> 9, nn = n & 511;
        const float* W = (which == 0) ? Wq : ((which == 1) ? Wk : Wv);
        WqkvT[idx] = f2bf(W[k * INNER_ + nn]);
        return;
    }
    idx -= total_wqkv;
    if (idx < total_wo) {
        int c = idx >> 9, k = idx & 511;
        WoT[idx] = f2bf(Wo[k * D_ + c]);
    }
}

// ---------------- fused QKV projection GEMM: [8192,256] x [256,1536] --------
__global__ __launch_bounds__(256) void proj_gemm(
    const ushort_t* __restrict__ xb, const ushort_t* __restrict__ WqkvT,
    ushort_t* __restrict__ Qb, ushort_t* __restrict__ Kb,
    ushort_t* __restrict__ Vb) {
    __shared__ ushort_t As[128][PAD];
    __shared__ ushort_t Bs[128][PAD];
    int bid = blockIdx.x;
    int tileN = bid % 12, tileM = bid / 12;
    int tid = threadIdx.x;
    int w = tid >> 6, lane = tid & 63, q = lane >> 4, r = lane & 15;
    int wr = (w & 1) * 64, wc = (w >> 1) * 64;
    float4v acc[4][4];
    for (int i = 0; i < 4; i++)
        for (int j = 0; j < 4; j++)
            for (int e = 0; e < 4; e++) acc[i][j][e] = 0.f;

    for (int k0 = 0; k0 < 256; k0 += 64) {
        for (int it = 0; it < 4; it++) {
            int idx = tid + it * 256;
            int row = idx >> 3, kc = (idx & 7) * 8;
            *(short8*)&As[row][kc] =
                *(const short8*)&xb[(size_t)(tileM * 128 + row) * 256 + k0 + kc];
            *(short8*)&Bs[row][kc] =
                *(const short8*)&WqkvT[(size_t)(tileN * 128 + row) * 256 + k0 + kc];
        }
        __syncthreads();
        for (int kk = 0; kk < 64; kk += 32) {
            short8 a[4], b[4];
            for (int mi = 0; mi < 4; mi++)
                a[mi] = *(const short8*)&As[wr + mi * 16 + r][kk + q * 8];
            for (int ni = 0; ni < 4; ni++)
                b[ni] = *(const short8*)&Bs[wc + ni * 16 + r][kk + q * 8];
            for (int mi = 0; mi < 4; mi++)
                for (int ni = 0; ni < 4; ni++)
                    acc[mi][ni] = __builtin_amdgcn_mfma_f32_16x16x32_bf16(
                        a[mi], b[ni], acc[mi][ni], 0, 0, 0);
        }
        __syncthreads();
    }
    for (int mi = 0; mi < 4; mi++)
        for (int ni = 0; ni < 4; ni++)
            for (int reg = 0; reg < 4; reg++) {
                int grow = tileM * 128 + wr + mi * 16 + q * 4 + reg;
                int gcol = tileN * 128 + wc + ni * 16 + r;
                float v = acc[mi][ni][reg];
                int which = gcol >> 9, inner = gcol & 511;
                int h = inner >> 6, d = inner & 63;
                int b = grow >> 12, n = grow & 4095;
                size_t off = (((size_t)(b * H_ + h)) * N_ + n) * DH_ + d;
                if (which == 0) Qb[off] = f2bf(v);
                else if (which == 1) Kb[off] = f2bf(v);
                else Vb[off] = f2bf(v);
            }
}

// ---------------- per-head LayerNorm + y init + transposed fp8 t0 -----------
__global__ __launch_bounds__(256) void ln_kernel(
    const ushort_t* __restrict__ Vb, const float* __restrict__ gamma,
    const float* __restrict__ beta, const float* __restrict__ coeffs,
    unsigned char* __restrict__ t0T, float* __restrict__ y) {
    int tid = threadIdx.x;
    int wave = tid >> 6, lane = tid & 63;
    size_t row = (size_t)blockIdx.x * 4 + wave;   // bh*4096 + n
    int bh = (int)(row >> 12), n = (int)(row & 4095);
    int h = bh & 7;
    float v = bf2f(Vb[row * 64 + lane]);
    float s = v;
    for (int m = 32; m >= 1; m >>= 1) s += __shfl_xor(s, m, 64);
    float mu = s * (1.f / 64.f);
    float dv = v - mu;
    float s2 = dv * dv;
    for (int m = 32; m >= 1; m >>= 1) s2 += __shfl_xor(s2, m, 64);
    float var = s2 * (1.f / 64.f);
    float vln = dv * rsqrtf(var + 1e-5f) * gamma[lane] + beta[lane];
    float c0 = coeffs[h * 4 + 0];
    y[row * 64 + lane] = c0 * vln;
    t0T[((size_t)bh * 64 + lane) * 4096 + n] = f2fp8s(vln);
}

// ---------------- E = exp(Q K^T / 8), fp8, coalesced dwordx4 stores ---------
__global__ __launch_bounds__(256) void s_kernel(
    const ushort_t* __restrict__ Qb, const ushort_t* __restrict__ Kb,
    unsigned char* __restrict__ E, int bh0) {
    __shared__ char smem[36864];
    ushort_t (*As)[PAD] = (ushort_t(*)[PAD])smem;            // Q tile 128x64
    ushort_t (*Bs)[PAD] = (ushort_t(*)[PAD])(smem + 18432);  // K tile 128x64
    unsigned int* E8 = (unsigned int*)smem;                   // 128 x 36 uints
    int bid = blockIdx.x;
    int local = bid >> 10;
    int rem = bid & 1023;
    int ti = rem >> 5, tj = rem & 31;
    int bh = bh0 + local;
    const ushort_t* Q = Qb + (size_t)bh * N_ * 64;
    const ushort_t* K = Kb + (size_t)bh * N_ * 64;
    unsigned char* Eg = E + (size_t)local * N_ * N_;
    int tid = threadIdx.x, w = tid >> 6, lane = tid & 63, q = lane >> 4, r = lane & 15;
    int wj = (w & 1) * 64, wi = (w >> 1) * 64;
    float4v acc[4][4];
    for (int i = 0; i < 4; i++)
        for (int j = 0; j < 4; j++)
            for (int e = 0; e < 4; e++) acc[i][j][e] = 0.f;

    for (int it = 0; it < 4; it++) {
        int idx = tid + it * 256;
        int row = idx >> 3, kc = (idx & 7) * 8;
        *(short8*)&As[row][kc] = *(const short8*)&Q[(size_t)(ti * 128 + row) * 64 + kc];
        *(short8*)&Bs[row][kc] = *(const short8*)&K[(size_t)(tj * 128 + row) * 64 + kc];
    }
    __syncthreads();
    for (int kk = 0; kk < 64; kk += 32) {
        short8 a[4], b[4];
        for (int mi = 0; mi < 4; mi++)             // A = K rows (j direction)
            a[mi] = *(const short8*)&Bs[wj + mi * 16 + r][kk + q * 8];
        for (int ni = 0; ni < 4; ni++)             // B = Q rows (i direction)
            b[ni] = *(const short8*)&As[wi + ni * 16 + r][kk + q * 8];
        for (int mi = 0; mi < 4; mi++)
            for (int ni = 0; ni < 4; ni++)
                acc[mi][ni] = __builtin_amdgcn_mfma_f32_16x16x32_bf16(
                    a[mi], b[ni], acc[mi][ni], 0, 0, 0);
    }
    __syncthreads();   // done with As/Bs; reuse as E8
    for (int mi = 0; mi < 4; mi++)
        for (int ni = 0; ni < 4; ni++) {
            float f0 = __expf(0.125f * acc[mi][ni][0]);
            float f1 = __expf(0.125f * acc[mi][ni][1]);
            float f2 = __expf(0.125f * acc[mi][ni][2]);
            float f3 = __expf(0.125f * acc[mi][ni][3]);
            int p = __builtin_amdgcn_cvt_pk_fp8_f32(f0, f1, 0, false);
            p = __builtin_amdgcn_cvt_pk_fp8_f32(f2, f3, p, true);
            int il = wi + ni * 16 + r;                       // E row i (local)
            int j4 = ((wj + mi * 16) >> 2) + q;              // E col / 4
            E8[il * 36 + j4] = (unsigned int)p;
        }
    __syncthreads();
    for (int it = 0; it < 4; it++) {
        int idx = tid + it * 256;                  // 0..1023
        int row = idx >> 3, c4 = (idx & 7) * 4;
        uint4v vv = *(const uint4v*)&E8[row * 36 + c4];
        *(uint4v*)&Eg[(size_t)(ti * 128 + row) * 4096 + tj * 128 + c4 * 4] = vv;
    }
}

// ---------------- filter partial: barrier-free K-loop -----------------------
// t chunk (64 d-rows x 1024 j) staged in LDS once; E rows streamed directly
// from global as MFMA A-fragments (no LDS, no barriers in the K-loop).
__global__ __launch_bounds__(256) void filter_p2(
    const unsigned char* __restrict__ E, const unsigned char* __restrict__ tinT,
    float* __restrict__ u, float* __restrict__ sbuf, int bh0, int ng) {
    __shared__ unsigned char Ts[64][TSTR];   // 66.5 KB
    int bid = blockIdx.x;
    int local = bid >> 8;              // 64 ti x SPLIT(4) = 256 blocks per bh
    int rem = bid & 255;
    int ti = rem >> 2;
    int quarter = rem & 3;
    const unsigned char* Eg = E + (size_t)local * N_ * N_;
    const unsigned char* tin = tinT + (size_t)(bh0 + local) * 64 * N_;
    int tid = threadIdx.x, w = tid >> 6, lane = tid & 63, q = lane >> 4, r = lane & 15;
    int kbeg = quarter * (N_ / SPLIT);   // chunk of 1024

    // stage t chunk: 64 KB, 256 threads x 16 iters x 16B, coalesced
    for (int it = 0; it < 16; it++) {
        int idx = tid + it * 256;            // 0..4095
        int row = idx >> 6;                  // 0..63 (d)
        int col = (idx & 63) * 16;           // 0..1008
        *(uint4v*)&Ts[row][col] =
            *(const uint4v*)&tin[(size_t)row * 4096 + kbeg + col];
    }
    __syncthreads();

    float4v acc[4], accs;
    for (int e = 0; e < 4; e++) accs[e] = 0.f;
    for (int j = 0; j < 4; j++)
        for (int e = 0; e < 4; e++) acc[j][e] = 0.f;
    const long bones = 0x3838383838383838L;  // 8x fp8(1.0)

    // this lane's E row pointer (A-fragment: row = w*16 + r, bytes k0 + q*8)
    const unsigned char* ep =
        Eg + (size_t)(ti * 64 + w * 16 + r) * 4096 + kbeg + q * 8;

#pragma unroll 4
    for (int k0 = 0; k0 < N_ / SPLIT; k0 += 32) {
        long a = *(const long*)(ep + k0);
        long b0 = *(const long*)&Ts[r][k0 + q * 8];
        long b1 = *(const long*)&Ts[16 + r][k0 + q * 8];
        long b2 = *(const long*)&Ts[32 + r][k0 + q * 8];
        long b3 = *(const long*)&Ts[48 + r][k0 + q * 8];
        acc[0] = __builtin_amdgcn_mfma_f32_16x16x32_fp8_fp8(a, b0, acc[0], 0, 0, 0);
        acc[1] = __builtin_amdgcn_mfma_f32_16x16x32_fp8_fp8(a, b1, acc[1], 0, 0, 0);
        acc[2] = __builtin_amdgcn_mfma_f32_16x16x32_fp8_fp8(a, b2, acc[2], 0, 0, 0);
        acc[3] = __builtin_amdgcn_mfma_f32_16x16x32_fp8_fp8(a, b3, acc[3], 0, 0, 0);
        accs   = __builtin_amdgcn_mfma_f32_16x16x32_fp8_fp8(a, bones, accs, 0, 0, 0);
    }

    float* ub = u + ((size_t)(quarter * ng + local)) * N_ * 64;
    float* sb = sbuf + ((size_t)(quarter * ng + local)) * N_;
    for (int reg = 0; reg < 4; reg++) {
        int grow = ti * 64 + w * 16 + q * 4 + reg;
        for (int ni = 0; ni < 4; ni++) {
            int gcol = ni * 16 + r;
            ub[(size_t)grow * 64 + gcol] = acc[ni][reg];
        }
        if (r == 0) sb[grow] = accs[reg];
    }
}

// ---------------- normalize: t = Σu/Σs ; y += ck t ; fp8 t out --------------
__global__ __launch_bounds__(256) void norm_kernel(
    const float* __restrict__ u, const float* __restrict__ sbuf,
    float* __restrict__ y, unsigned char* __restrict__ toutT,
    const float* __restrict__ coeffs, int bh0, int ng, int kidx, int write_t) {
    int tid = threadIdx.x;
    int wave = tid >> 6, lane = tid & 63;
    size_t idx = (size_t)blockIdx.x * 4 + wave;   // local*4096 + n
    int local = (int)(idx >> 12), n = (int)(idx & 4095);
    int bh = bh0 + local;
    int h = bh & 7;
    float ck = coeffs[h * 4 + kidx];
    float us = 0.f, ss = 0.f;
    for (int sp = 0; sp < SPLIT; sp++) {
        us += u[((size_t)(sp * ng + local) * N_ + n) * 64 + lane];
        ss += sbuf[(size_t)(sp * ng + local) * N_ + n];
    }
    float t = us / ss;
    y[((size_t)bh * N_ + n) * 64 + lane] += ck * t;
    if (write_t)
        toutT[((size_t)bh * 64 + lane) * N_ + n] = f2fp8s(t);
}

// ---------------- output projection: merged[8192,512] x Wo[512,256] ---------
__global__ __launch_bounds__(256) void out_gemm(
    const float* __restrict__ y, const ushort_t* __restrict__ WoT,
    float* __restrict__ out) {
    __shared__ ushort_t As[128][PAD];
    __shared__ ushort_t Bs[64][PAD];
    int bid = blockIdx.x;
    int tileN = bid & 3, tileM = bid >> 2;
    int tid = threadIdx.x, w = tid >> 6, lane = tid & 63, q = lane >> 4, r = lane & 15;
    int wr = w * 32;
    float4v acc[2][4];
    for (int i = 0; i < 2; i++)
        for (int j = 0; j < 4; j++)
            for (int e = 0; e < 4; e++) acc[i][j][e] = 0.f;

    for (int k0 = 0; k0 < 512; k0 += 64) {
        int h = k0 >> 6;
        for (int it = 0; it < 8; it++) {
            int idx = tid + it * 256;
            int row = idx >> 4, kc = (idx & 15) * 4;
            int grow = tileM * 128 + row;
            int b = grow >> 12, n = grow & 4095;
            const float4* src =
                (const float4*)&y[(((size_t)(b * H_ + h)) * N_ + n) * 64 + kc];
            float4 v = *src;
            ushort4v pv;
            pv[0] = f2bf(v.x); pv[1] = f2bf(v.y); pv[2] = f2bf(v.z); pv[3] = f2bf(v.w);
            *(ushort4v*)&As[row][kc] = pv;
        }
        for (int it = 0; it < 2; it++) {
            int idx = tid + it * 256;
            int row = idx >> 3, kc = (idx & 7) * 8;
            *(short8*)&Bs[row][kc] =
                *(const short8*)&WoT[(size_t)(tileN * 64 + row) * 512 + k0 + kc];
        }
        __syncthreads();
        for (int kk = 0; kk < 64; kk += 32) {
            short8 a[2], b[4];
            a[0] = *(const short8*)&As[wr + r][kk + q * 8];
            a[1] = *(const short8*)&As[wr + 16 + r][kk + q * 8];
            for (int ni = 0; ni < 4; ni++)
                b[ni] = *(const short8*)&Bs[ni * 16 + r][kk + q * 8];
            for (int mi = 0; mi < 2; mi++)
                for (int ni = 0; ni < 4; ni++)
                    acc[mi][ni] = __builtin_amdgcn_mfma_f32_16x16x32_bf16(
                        a[mi], b[ni], acc[mi][ni], 0, 0, 0);
        }
        __syncthreads();
    }
    for (int mi = 0; mi < 2; mi++)
        for (int reg = 0; reg < 4; reg++) {
            int grow = tileM * 128 + wr + mi * 16 + q * 4 + reg;
            for (int ni = 0; ni < 4; ni++) {
                int gcol = tileN * 64 + ni * 16 + r;
                out[(size_t)grow * 256 + gcol] = acc[mi][ni][reg];
            }
        }
}

// ---------------------------------------------------------------------------
extern "C" void kernel_launch(void* const* d_in, const int* in_sizes, int n_in,
                              void* d_out, int out_size, void* d_ws, size_t ws_size,
                              hipStream_t stream) {
    const float* x      = (const float*)d_in[0];
    const float* Wq     = (const float*)d_in[1];
    const float* Wk     = (const float*)d_in[2];
    const float* Wv     = (const float*)d_in[3];
    const float* Wo     = (const float*)d_in[4];
    const float* gamma  = (const float*)d_in[5];
    const float* beta   = (const float*)d_in[6];
    const float* coeffs = (const float*)d_in[7];
    float* out = (float*)d_out;

    char* ws = (char*)d_ws;
    size_t off = 0;
    auto alloc = [&](size_t bytes) -> void* {
        void* p = ws + off;
        off += (bytes + 255) & ~(size_t)255;
        return p;
    };
    ushort_t* xb    = (ushort_t*)alloc((size_t)B_ * N_ * D_ * 2);
    ushort_t* WqkvT = (ushort_t*)alloc((size_t)3 * INNER_ * D_ * 2);
    ushort_t* WoT   = (ushort_t*)alloc((size_t)D_ * INNER_ * 2);
    ushort_t* Qb    = (ushort_t*)alloc((size_t)NBH * N_ * DH_ * 2);
    ushort_t* Kb    = (ushort_t*)alloc((size_t)NBH * N_ * DH_ * 2);
    unsigned char* t0T = (unsigned char*)alloc((size_t)NBH * DH_ * N_);
    unsigned char* t1T = (unsigned char*)alloc((size_t)NBH * DH_ * N_);
    float*    y     = (float*)alloc((size_t)NBH * N_ * DH_ * 4);

    const size_t E1 = (size_t)N_ * N_;  // 16.78 MB per (b,h) in fp8
    int nbh_g = 8;
    while (nbh_g > 1) {
        size_t need = off + (size_t)SPLIT * nbh_g * N_ * DH_ * 4
                      + (size_t)SPLIT * nbh_g * N_ * 4 + 1024
                      + (size_t)nbh_g * E1;
        if (need <= ws_size) break;
        nbh_g >>= 1;
    }
    float* u    = (float*)alloc((size_t)SPLIT * nbh_g * N_ * DH_ * 4);
    float* sbuf = (float*)alloc((size_t)SPLIT * nbh_g * N_ * 4);
    unsigned char* E = (unsigned char*)(ws + off);
    // V (bf16, 8.4 MB) aliased onto the E region: dead once ln_kernel has run,
    // before the first s_kernel write.
    ushort_t* Vb = (ushort_t*)E;

    const int prep_total = B_ * N_ * D_ + 3 * INNER_ * D_ + D_ * INNER_;
    prep_kernel<<<(prep_total + 255) / 256, 256, 0, stream>>>(
        x, Wq, Wk, Wv, Wo, xb, WqkvT, WoT);
    proj_gemm<<<768, 256, 0, stream>>>(xb, WqkvT, Qb, Kb, Vb);
    ln_kernel<<<(NBH * N_) / 4, 256, 0, stream>>>(Vb, gamma, beta, coeffs, t0T, y);

    int fgrid = nbh_g * 64 * SPLIT;
    int ngrid = (nbh_g * N_) / 4;

    for (int bh0 = 0; bh0 < NBH; bh0 += nbh_g) {
        s_kernel<<<nbh_g * 1024, 256, 0, stream>>>(Qb, Kb, E, bh0);
        filter_p2<<<fgrid, 256, 0, stream>>>(E, t0T, u, sbuf, bh0, nbh_g);
        norm_kernel<<<ngrid, 256, 0, stream>>>(u, sbuf, y, t1T, coeffs, bh0, nbh_g, 1, 1);
        filter_p2<<<fgrid, 256, 0, stream>>>(E, t1T, u, sbuf, bh0, nbh_g);
        norm_kernel<<<ngrid, 256, 0, stream>>>(u, sbuf, y, t0T, coeffs, bh0, nbh_g, 2, 1);
        filter_p2<<<fgrid, 256, 0, stream>>>(E, t0T, u, sbuf, bh0, nbh_g);
        norm_kernel<<<ngrid, 256, 0, stream>>>(u, sbuf, y, t1T, coeffs, bh0, nbh_g, 3, 0);
    }
    out_gemm<<<256, 256, 0, stream>>>(y, WoT, out);
}

// Round 9
// 538.514 us; speedup vs baseline: 1.0990x; 1.0990x over previous
//
#include <hip/hip_runtime.h>
#include <stdint.h>

#define B_ 2
#define N_ 4096
#define D_ 256
#define H_ 8
#define DH_ 64
#define INNER_ 512
#define NBH 16
#define PAD 72
#define SPLIT 2

typedef unsigned short ushort_t;
typedef __attribute__((ext_vector_type(8))) short short8;
typedef __attribute__((ext_vector_type(4))) float float4v;
typedef __attribute__((ext_vector_type(4))) unsigned short ushort4v;
typedef __attribute__((ext_vector_type(4))) unsigned int uint4v;

__device__ __forceinline__ ushort_t f2bf(float f) {
    union { float f; unsigned int u; } v; v.f = f;
    unsigned int r = v.u + 0x7FFFu + ((v.u >> 16) & 1u);
    return (ushort_t)(r >> 16);
}
__device__ __forceinline__ float bf2f(ushort_t u) {
    union { unsigned int u; float f; } v; v.u = ((unsigned int)u) << 16;
    return v.f;
}
// full signed fp8 e4m3 encode with subnormal + clamp handling (for t values)
__device__ __forceinline__ unsigned char f2fp8s(float f) {
    union { float f; unsigned int u; } v; v.f = f;
    unsigned int s = (v.u >> 24) & 0x80u;
    v.u &= 0x7FFFFFFFu;
    float a = v.f;
    if (a >= 448.f) return (unsigned char)(s | 0x7E);
    if (a < 0.015625f) {
        int m = (int)(a * 512.f + 0.5f);
        return (unsigned char)(s | (unsigned)m);
    }
    unsigned int u = v.u + 0x7FFFFu + ((v.u >> 20) & 1u);
    return (unsigned char)(s | (((u >> 20) & 0x7FF) - 960));
}

// fragment-interleaved byte offset for a (row, col) within one bh's 4096x4096
// fp8 matrix: 512B fragments F = (row>>4)*128 + (col>>5); within-fragment
// byte = (row&15)*32 + (col&31).
__device__ __forceinline__ size_t frag_off(int row, int col) {
    return ((size_t)(row >> 4) * 128 + (col >> 5)) * 512 + (row & 15) * 32 + (col & 31);
}

// ---------------- prep: bf16 conversions + weight transposes ----------------
__global__ __launch_bounds__(256) void prep_kernel(
    const float* __restrict__ x, const float* __restrict__ Wq,
    const float* __restrict__ Wk, const float* __restrict__ Wv,
    const float* __restrict__ Wo,
    ushort_t* __restrict__ xb, ushort_t* __restrict__ WqkvT,
    ushort_t* __restrict__ WoT) {
    int idx = blockIdx.x * 256 + threadIdx.x;
    const int total_x = B_ * N_ * D_;
    const int total_wqkv = 3 * INNER_ * D_;
    const int total_wo = D_ * INNER_;
    if (idx < total_x) { xb[idx] = f2bf(x[idx]); return; }
    idx -= total_x;
    if (idx < total_wqkv) {
        int n = idx >> 8, k = idx & 255;
        int which = n >> 9, nn = n & 511;
        const float* W = (which == 0) ? Wq : ((which == 1) ? Wk : Wv);
        WqkvT[idx] = f2bf(W[k * INNER_ + nn]);
        return;
    }
    idx -= total_wqkv;
    if (idx < total_wo) {
        int c = idx >> 9, k = idx & 511;
        WoT[idx] = f2bf(Wo[k * D_ + c]);
    }
}

// ---------------- fused QKV projection GEMM: [8192,256] x [256,1536] --------
__global__ __launch_bounds__(256) void proj_gemm(
    const ushort_t* __restrict__ xb, const ushort_t* __restrict__ WqkvT,
    ushort_t* __restrict__ Qb, ushort_t* __restrict__ Kb,
    ushort_t* __restrict__ Vb) {
    __shared__ ushort_t As[128][PAD];
    __shared__ ushort_t Bs[128][PAD];
    int bid = blockIdx.x;
    int tileN = bid % 12, tileM = bid / 12;
    int tid = threadIdx.x;
    int w = tid >> 6, lane = tid & 63, q = lane >> 4, r = lane & 15;
    int wr = (w & 1) * 64, wc = (w >> 1) * 64;
    float4v acc[4][4];
    for (int i = 0; i < 4; i++)
        for (int j = 0; j < 4; j++)
            for (int e = 0; e < 4; e++) acc[i][j][e] = 0.f;

    for (int k0 = 0; k0 < 256; k0 += 64) {
        for (int it = 0; it < 4; it++) {
            int idx = tid + it * 256;
            int row = idx >> 3, kc = (idx & 7) * 8;
            *(short8*)&As[row][kc] =
                *(const short8*)&xb[(size_t)(tileM * 128 + row) * 256 + k0 + kc];
            *(short8*)&Bs[row][kc] =
                *(const short8*)&WqkvT[(size_t)(tileN * 128 + row) * 256 + k0 + kc];
        }
        __syncthreads();
        for (int kk = 0; kk < 64; kk += 32) {
            short8 a[4], b[4];
            for (int mi = 0; mi < 4; mi++)
                a[mi] = *(const short8*)&As[wr + mi * 16 + r][kk + q * 8];
            for (int ni = 0; ni < 4; ni++)
                b[ni] = *(const short8*)&Bs[wc + ni * 16 + r][kk + q * 8];
            for (int mi = 0; mi < 4; mi++)
                for (int ni = 0; ni < 4; ni++)
                    acc[mi][ni] = __builtin_amdgcn_mfma_f32_16x16x32_bf16(
                        a[mi], b[ni], acc[mi][ni], 0, 0, 0);
        }
        __syncthreads();
    }
    for (int mi = 0; mi < 4; mi++)
        for (int ni = 0; ni < 4; ni++)
            for (int reg = 0; reg < 4; reg++) {
                int grow = tileM * 128 + wr + mi * 16 + q * 4 + reg;
                int gcol = tileN * 128 + wc + ni * 16 + r;
                float v = acc[mi][ni][reg];
                int which = gcol >> 9, inner = gcol & 511;
                int h = inner >> 6, d = inner & 63;
                int b = grow >> 12, n = grow & 4095;
                size_t off = (((size_t)(b * H_ + h)) * N_ + n) * DH_ + d;
                if (which == 0) Qb[off] = f2bf(v);
                else if (which == 1) Kb[off] = f2bf(v);
                else Vb[off] = f2bf(v);
            }
}

// ---------------- per-head LayerNorm + y init + fragment-layout fp8 t0 ------
__global__ __launch_bounds__(256) void ln_kernel(
    const ushort_t* __restrict__ Vb, const float* __restrict__ gamma,
    const float* __restrict__ beta, const float* __restrict__ coeffs,
    unsigned char* __restrict__ t0T, float* __restrict__ y) {
    int tid = threadIdx.x;
    int wave = tid >> 6, lane = tid & 63;
    size_t row = (size_t)blockIdx.x * 4 + wave;   // bh*4096 + n
    int bh = (int)(row >> 12), n = (int)(row & 4095);
    int h = bh & 7;
    float v = bf2f(Vb[row * 64 + lane]);
    float s = v;
    for (int m = 32; m >= 1; m >>= 1) s += __shfl_xor(s, m, 64);
    float mu = s * (1.f / 64.f);
    float dv = v - mu;
    float s2 = dv * dv;
    for (int m = 32; m >= 1; m >>= 1) s2 += __shfl_xor(s2, m, 64);
    float var = s2 * (1.f / 64.f);
    float vln = dv * rsqrtf(var + 1e-5f) * gamma[lane] + beta[lane];
    float c0 = coeffs[h * 4 + 0];
    y[row * 64 + lane] = c0 * vln;
    // t': fragments (d_blk=lane>>4)*128 + (n>>5), byte (lane&15)*32 + (n&31)
    t0T[(size_t)bh * 262144 +
        ((size_t)(lane >> 4) * 128 + (n >> 5)) * 512 + (lane & 15) * 32 + (n & 31)]
        = f2fp8s(vln);
}

// ---------------- E = exp(Q K^T / 8), fp8, fragment-interleaved layout ------
__global__ __launch_bounds__(256) void s_kernel(
    const ushort_t* __restrict__ Qb, const ushort_t* __restrict__ Kb,
    unsigned char* __restrict__ E, int bh0) {
    __shared__ char smem[36864];
    ushort_t (*As)[PAD] = (ushort_t(*)[PAD])smem;            // Q tile 128x64
    ushort_t (*Bs)[PAD] = (ushort_t(*)[PAD])(smem + 18432);  // K tile 128x64
    unsigned int* E8 = (unsigned int*)smem;                   // 128 x 36 uints
    int bid = blockIdx.x;
    int local = bid >> 10;
    int rem = bid & 1023;
    int ti = rem >> 5, tj = rem & 31;
    int bh = bh0 + local;
    const ushort_t* Q = Qb + (size_t)bh * N_ * 64;
    const ushort_t* K = Kb + (size_t)bh * N_ * 64;
    unsigned char* Eg = E + (size_t)local * N_ * N_;
    int tid = threadIdx.x, w = tid >> 6, lane = tid & 63, q = lane >> 4, r = lane & 15;
    int wj = (w & 1) * 64, wi = (w >> 1) * 64;
    float4v acc[4][4];
    for (int i = 0; i < 4; i++)
        for (int j = 0; j < 4; j++)
            for (int e = 0; e < 4; e++) acc[i][j][e] = 0.f;

    for (int it = 0; it < 4; it++) {
        int idx = tid + it * 256;
        int row = idx >> 3, kc = (idx & 7) * 8;
        *(short8*)&As[row][kc] = *(const short8*)&Q[(size_t)(ti * 128 + row) * 64 + kc];
        *(short8*)&Bs[row][kc] = *(const short8*)&K[(size_t)(tj * 128 + row) * 64 + kc];
    }
    __syncthreads();
    for (int kk = 0; kk < 64; kk += 32) {
        short8 a[4], b[4];
        for (int mi = 0; mi < 4; mi++)             // A = K rows (j direction)
            a[mi] = *(const short8*)&Bs[wj + mi * 16 + r][kk + q * 8];
        for (int ni = 0; ni < 4; ni++)             // B = Q rows (i direction)
            b[ni] = *(const short8*)&As[wi + ni * 16 + r][kk + q * 8];
        for (int mi = 0; mi < 4; mi++)
            for (int ni = 0; ni < 4; ni++)
                acc[mi][ni] = __builtin_amdgcn_mfma_f32_16x16x32_bf16(
                    a[mi], b[ni], acc[mi][ni], 0, 0, 0);
    }
    __syncthreads();   // done with As/Bs; reuse as E8
    for (int mi = 0; mi < 4; mi++)
        for (int ni = 0; ni < 4; ni++) {
            float f0 = __expf(0.125f * acc[mi][ni][0]);
            float f1 = __expf(0.125f * acc[mi][ni][1]);
            float f2 = __expf(0.125f * acc[mi][ni][2]);
            float f3 = __expf(0.125f * acc[mi][ni][3]);
            int p = __builtin_amdgcn_cvt_pk_fp8_f32(f0, f1, 0, false);
            p = __builtin_amdgcn_cvt_pk_fp8_f32(f2, f3, p, true);
            int il = wi + ni * 16 + r;                       // E row i (local)
            int j4 = ((wj + mi * 16) >> 2) + q;              // E col / 4
            E8[il * 36 + j4] = (unsigned int)p;
        }
    __syncthreads();
    // write fragment-interleaved: 32 fragments (8 row_blk x 4 k_blk) x 512B
    for (int it = 0; it < 4; it++) {
        int idx = tid + it * 256;                  // 0..1023
        int f = idx >> 5;                          // fragment 0..31
        int rb = f >> 2, kb = f & 3;
        int o = (idx & 31) * 16;                   // byte offset within fragment
        int il = rb * 16 + (o >> 5);               // local row
        int j4 = kb * 8 + ((o & 31) >> 2);         // local col / 4
        uint4v vv = *(const uint4v*)&E8[il * 36 + j4];
        *(uint4v*)&Eg[((size_t)((ti * 8 + rb) * 128 + (tj * 4 + kb))) * 512 + o] = vv;
    }
}

// ---------------- filter partial: LDS-free, barrier-free K-loop -------------
// E and t both fragment-interleaved; each wave streams its A-fragments and
// the 4 t B-fragments directly from global (512B-contiguous per wave-load).
__global__ __launch_bounds__(256) void filter_p2(
    const unsigned char* __restrict__ E, const unsigned char* __restrict__ tinT,
    float* __restrict__ u, float* __restrict__ sbuf, int bh0, int ng) {
    int bid = blockIdx.x;
    int local = bid >> 7;              // 64 ti x SPLIT(2) = 128 blocks per bh
    int rem = bid & 127;
    int ti = rem >> 1;
    int half = rem & 1;
    const unsigned char* Eg = E + (size_t)local * N_ * N_;
    const unsigned char* tin = tinT + (size_t)(bh0 + local) * 262144;
    int tid = threadIdx.x, w = tid >> 6, lane = tid & 63, q = lane >> 4, r = lane & 15;
    int off = r * 32 + q * 8;
    int kb0 = half * ((N_ / SPLIT) >> 5);   // starting k_blk

    const unsigned char* ep =
        Eg + ((size_t)(ti * 4 + w) * 128 + kb0) * 512 + off;
    const unsigned char* tp = tin + (size_t)kb0 * 512 + off;

    float4v acc[4], accs;
    for (int e = 0; e < 4; e++) accs[e] = 0.f;
    for (int j = 0; j < 4; j++)
        for (int e = 0; e < 4; e++) acc[j][e] = 0.f;
    const long bones = 0x3838383838383838L;  // 8x fp8(1.0)

    const int KI = (N_ / SPLIT) / 32;   // 64 fragment-steps
#pragma unroll 4
    for (int k = 0; k < KI; k++) {
        long a  = *(const long*)(ep + (size_t)k * 512);
        long b0 = *(const long*)(tp + (size_t)k * 512);
        long b1 = *(const long*)(tp + (size_t)k * 512 + 65536);   // d_blk 1
        long b2 = *(const long*)(tp + (size_t)k * 512 + 131072);  // d_blk 2
        long b3 = *(const long*)(tp + (size_t)k * 512 + 196608);  // d_blk 3
        acc[0] = __builtin_amdgcn_mfma_f32_16x16x32_fp8_fp8(a, b0, acc[0], 0, 0, 0);
        acc[1] = __builtin_amdgcn_mfma_f32_16x16x32_fp8_fp8(a, b1, acc[1], 0, 0, 0);
        acc[2] = __builtin_amdgcn_mfma_f32_16x16x32_fp8_fp8(a, b2, acc[2], 0, 0, 0);
        acc[3] = __builtin_amdgcn_mfma_f32_16x16x32_fp8_fp8(a, b3, acc[3], 0, 0, 0);
        accs   = __builtin_amdgcn_mfma_f32_16x16x32_fp8_fp8(a, bones, accs, 0, 0, 0);
    }

    float* ub = u + ((size_t)(half * ng + local)) * N_ * 64;
    float* sb = sbuf + ((size_t)(half * ng + local)) * N_;
    for (int reg = 0; reg < 4; reg++) {
        int grow = ti * 64 + w * 16 + q * 4 + reg;
        for (int ni = 0; ni < 4; ni++) {
            int gcol = ni * 16 + r;
            ub[(size_t)grow * 64 + gcol] = acc[ni][reg];
        }
        if (r == 0) sb[grow] = accs[reg];
    }
}

// ---------------- normalize: t = Σu/Σs ; y += ck t ; fragment fp8 t out -----
__global__ __launch_bounds__(256) void norm_kernel(
    const float* __restrict__ u, const float* __restrict__ sbuf,
    float* __restrict__ y, unsigned char* __restrict__ toutT,
    const float* __restrict__ coeffs, int bh0, int ng, int kidx, int write_t) {
    int tid = threadIdx.x;
    int wave = tid >> 6, lane = tid & 63;
    size_t idx = (size_t)blockIdx.x * 4 + wave;   // local*4096 + n
    int local = (int)(idx >> 12), n = (int)(idx & 4095);
    int bh = bh0 + local;
    int h = bh & 7;
    float ck = coeffs[h * 4 + kidx];
    float us = 0.f, ss = 0.f;
    for (int sp = 0; sp < SPLIT; sp++) {
        us += u[((size_t)(sp * ng + local) * N_ + n) * 64 + lane];
        ss += sbuf[(size_t)(sp * ng + local) * N_ + n];
    }
    float t = us / ss;
    y[((size_t)bh * N_ + n) * 64 + lane] += ck * t;
    if (write_t)
        toutT[(size_t)bh * 262144 +
              ((size_t)(lane >> 4) * 128 + (n >> 5)) * 512 + (lane & 15) * 32 + (n & 31)]
            = f2fp8s(t);
}

// ---------------- output projection: merged[8192,512] x Wo[512,256] ---------
__global__ __launch_bounds__(256) void out_gemm(
    const float* __restrict__ y, const ushort_t* __restrict__ WoT,
    float* __restrict__ out) {
    __shared__ ushort_t As[128][PAD];
    __shared__ ushort_t Bs[64][PAD];
    int bid = blockIdx.x;
    int tileN = bid & 3, tileM = bid >> 2;
    int tid = threadIdx.x, w = tid >> 6, lane = tid & 63, q = lane >> 4, r = lane & 15;
    int wr = w * 32;
    float4v acc[2][4];
    for (int i = 0; i < 2; i++)
        for (int j = 0; j < 4; j++)
            for (int e = 0; e < 4; e++) acc[i][j][e] = 0.f;

    for (int k0 = 0; k0 < 512; k0 += 64) {
        int h = k0 >> 6;
        for (int it = 0; it < 8; it++) {
            int idx = tid + it * 256;
            int row = idx >> 4, kc = (idx & 15) * 4;
            int grow = tileM * 128 + row;
            int b = grow >> 12, n = grow & 4095;
            const float4* src =
                (const float4*)&y[(((size_t)(b * H_ + h)) * N_ + n) * 64 + kc];
            float4 v = *src;
            ushort4v pv;
            pv[0] = f2bf(v.x); pv[1] = f2bf(v.y); pv[2] = f2bf(v.z); pv[3] = f2bf(v.w);
            *(ushort4v*)&As[row][kc] = pv;
        }
        for (int it = 0; it < 2; it++) {
            int idx = tid + it * 256;
            int row = idx >> 3, kc = (idx & 7) * 8;
            *(short8*)&Bs[row][kc] =
                *(const short8*)&WoT[(size_t)(tileN * 64 + row) * 512 + k0 + kc];
        }
        __syncthreads();
        for (int kk = 0; kk < 64; kk += 32) {
            short8 a[2], b[4];
            a[0] = *(const short8*)&As[wr + r][kk + q * 8];
            a[1] = *(const short8*)&As[wr + 16 + r][kk + q * 8];
            for (int ni = 0; ni < 4; ni++)
                b[ni] = *(const short8*)&Bs[ni * 16 + r][kk + q * 8];
            for (int mi = 0; mi < 2; mi++)
                for (int ni = 0; ni < 4; ni++)
                    acc[mi][ni] = __builtin_amdgcn_mfma_f32_16x16x32_bf16(
                        a[mi], b[ni], acc[mi][ni], 0, 0, 0);
        }
        __syncthreads();
    }
    for (int mi = 0; mi < 2; mi++)
        for (int reg = 0; reg < 4; reg++) {
            int grow = tileM * 128 + wr + mi * 16 + q * 4 + reg;
            for (int ni = 0; ni < 4; ni++) {
                int gcol = tileN * 64 + ni * 16 + r;
                out[(size_t)grow * 256 + gcol] = acc[mi][ni][reg];
            }
        }
}

// ---------------------------------------------------------------------------
extern "C" void kernel_launch(void* const* d_in, const int* in_sizes, int n_in,
                              void* d_out, int out_size, void* d_ws, size_t ws_size,
                              hipStream_t stream) {
    const float* x      = (const float*)d_in[0];
    const float* Wq     = (const float*)d_in[1];
    const float* Wk     = (const float*)d_in[2];
    const float* Wv     = (const float*)d_in[3];
    const float* Wo     = (const float*)d_in[4];
    const float* gamma  = (const float*)d_in[5];
    const float* beta   = (const float*)d_in[6];
    const float* coeffs = (const float*)d_in[7];
    float* out = (float*)d_out;

    char* ws = (char*)d_ws;
    size_t off = 0;
    auto alloc = [&](size_t bytes) -> void* {
        void* p = ws + off;
        off += (bytes + 255) & ~(size_t)255;
        return p;
    };
    ushort_t* xb    = (ushort_t*)alloc((size_t)B_ * N_ * D_ * 2);
    ushort_t* WqkvT = (ushort_t*)alloc((size_t)3 * INNER_ * D_ * 2);
    ushort_t* WoT   = (ushort_t*)alloc((size_t)D_ * INNER_ * 2);
    ushort_t* Qb    = (ushort_t*)alloc((size_t)NBH * N_ * DH_ * 2);
    ushort_t* Kb    = (ushort_t*)alloc((size_t)NBH * N_ * DH_ * 2);
    unsigned char* t0T = (unsigned char*)alloc((size_t)NBH * DH_ * N_);
    unsigned char* t1T = (unsigned char*)alloc((size_t)NBH * DH_ * N_);
    float*    y     = (float*)alloc((size_t)NBH * N_ * DH_ * 4);

    const size_t E1 = (size_t)N_ * N_;  // 16.78 MB per (b,h) in fp8
    int nbh_g = 8;
    while (nbh_g > 1) {
        size_t need = off + (size_t)SPLIT * nbh_g * N_ * DH_ * 4
                      + (size_t)SPLIT * nbh_g * N_ * 4 + 1024
                      + (size_t)nbh_g * E1;
        if (need <= ws_size) break;
        nbh_g >>= 1;
    }
    float* u    = (float*)alloc((size_t)SPLIT * nbh_g * N_ * DH_ * 4);
    float* sbuf = (float*)alloc((size_t)SPLIT * nbh_g * N_ * 4);
    unsigned char* E = (unsigned char*)(ws + off);
    // V (bf16, 8.4 MB) aliased onto the E region: dead once ln_kernel has run,
    // before the first s_kernel write.
    ushort_t* Vb = (ushort_t*)E;

    const int prep_total = B_ * N_ * D_ + 3 * INNER_ * D_ + D_ * INNER_;
    prep_kernel<<<(prep_total + 255) / 256, 256, 0, stream>>>(
        x, Wq, Wk, Wv, Wo, xb, WqkvT, WoT);
    proj_gemm<<<768, 256, 0, stream>>>(xb, WqkvT, Qb, Kb, Vb);
    ln_kernel<<<(NBH * N_) / 4, 256, 0, stream>>>(Vb, gamma, beta, coeffs, t0T, y);

    int fgrid = nbh_g * 64 * SPLIT;
    int ngrid = (nbh_g * N_) / 4;

    for (int bh0 = 0; bh0 < NBH; bh0 += nbh_g) {
        s_kernel<<<nbh_g * 1024, 256, 0, stream>>>(Qb, Kb, E, bh0);
        filter_p2<<<fgrid, 256, 0, stream>>>(E, t0T, u, sbuf, bh0, nbh_g);
        norm_kernel<<<ngrid, 256, 0, stream>>>(u, sbuf, y, t1T, coeffs, bh0, nbh_g, 1, 1);
        filter_p2<<<fgrid, 256, 0, stream>>>(E, t1T, u, sbuf, bh0, nbh_g);
        norm_kernel<<<ngrid, 256, 0, stream>>>(u, sbuf, y, t0T, coeffs, bh0, nbh_g, 2, 1);
        filter_p2<<<fgrid, 256, 0, stream>>>(E, t0T, u, sbuf, bh0, nbh_g);
        norm_kernel<<<ngrid, 256, 0, stream>>>(u, sbuf, y, t1T, coeffs, bh0, nbh_g, 3, 0);
    }
    out_gemm<<<256, 256, 0, stream>>>(y, WoT, out);
}

// Round 10
// 522.059 us; speedup vs baseline: 1.1336x; 1.0315x over previous
//
#include <hip/hip_runtime.h>
#include <stdint.h>

#define B_ 2
#define N_ 4096
#define D_ 256
#define H_ 8
#define DH_ 64
#define INNER_ 512
#define NBH 16
#define PAD 72
#define SPLIT 4

typedef unsigned short ushort_t;
typedef __attribute__((ext_vector_type(8))) short short8;
typedef __attribute__((ext_vector_type(4))) float float4v;
typedef __attribute__((ext_vector_type(4))) unsigned short ushort4v;
typedef __attribute__((ext_vector_type(4))) unsigned int uint4v;

__device__ __forceinline__ ushort_t f2bf(float f) {
    union { float f; unsigned int u; } v; v.f = f;
    unsigned int r = v.u + 0x7FFFu + ((v.u >> 16) & 1u);
    return (ushort_t)(r >> 16);
}
__device__ __forceinline__ float bf2f(ushort_t u) {
    union { unsigned int u; float f; } v; v.u = ((unsigned int)u) << 16;
    return v.f;
}
// full signed fp8 e4m3 encode with subnormal + clamp handling (for t values)
__device__ __forceinline__ unsigned char f2fp8s(float f) {
    union { float f; unsigned int u; } v; v.f = f;
    unsigned int s = (v.u >> 24) & 0x80u;
    v.u &= 0x7FFFFFFFu;
    float a = v.f;
    if (a >= 448.f) return (unsigned char)(s | 0x7E);
    if (a < 0.015625f) {
        int m = (int)(a * 512.f + 0.5f);
        return (unsigned char)(s | (unsigned)m);
    }
    unsigned int u = v.u + 0x7FFFFu + ((v.u >> 20) & 1u);
    return (unsigned char)(s | (((u >> 20) & 0x7FF) - 960));
}

// ---------------- prep: bf16 conversions + weight transposes ----------------
__global__ __launch_bounds__(256) void prep_kernel(
    const float* __restrict__ x, const float* __restrict__ Wq,
    const float* __restrict__ Wk, const float* __restrict__ Wv,
    const float* __restrict__ Wo,
    ushort_t* __restrict__ xb, ushort_t* __restrict__ WqkvT,
    ushort_t* __restrict__ WoT) {
    int idx = blockIdx.x * 256 + threadIdx.x;
    const int total_x = B_ * N_ * D_;
    const int total_wqkv = 3 * INNER_ * D_;
    const int total_wo = D_ * INNER_;
    if (idx < total_x) { xb[idx] = f2bf(x[idx]); return; }
    idx -= total_x;
    if (idx < total_wqkv) {
        int n = idx >> 8, k = idx & 255;
        int which = n >> 9, nn = n & 511;
        const float* W = (which == 0) ? Wq : ((which == 1) ? Wk : Wv);
        WqkvT[idx] = f2bf(W[k * INNER_ + nn]);
        return;
    }
    idx -= total_wqkv;
    if (idx < total_wo) {
        int c = idx >> 9, k = idx & 511;
        WoT[idx] = f2bf(Wo[k * D_ + c]);
    }
}

// ---------------- fused QKV projection GEMM: [8192,256] x [256,1536] --------
__global__ __launch_bounds__(256) void proj_gemm(
    const ushort_t* __restrict__ xb, const ushort_t* __restrict__ WqkvT,
    ushort_t* __restrict__ Qb, ushort_t* __restrict__ Kb,
    ushort_t* __restrict__ Vb) {
    __shared__ ushort_t As[128][PAD];
    __shared__ ushort_t Bs[128][PAD];
    int bid = blockIdx.x;
    int tileN = bid % 12, tileM = bid / 12;
    int tid = threadIdx.x;
    int w = tid >> 6, lane = tid & 63, q = lane >> 4, r = lane & 15;
    int wr = (w & 1) * 64, wc = (w >> 1) * 64;
    float4v acc[4][4];
    for (int i = 0; i < 4; i++)
        for (int j = 0; j < 4; j++)
            for (int e = 0; e < 4; e++) acc[i][j][e] = 0.f;

    for (int k0 = 0; k0 < 256; k0 += 64) {
        for (int it = 0; it < 4; it++) {
            int idx = tid + it * 256;
            int row = idx >> 3, kc = (idx & 7) * 8;
            *(short8*)&As[row][kc] =
                *(const short8*)&xb[(size_t)(tileM * 128 + row) * 256 + k0 + kc];
            *(short8*)&Bs[row][kc] =
                *(const short8*)&WqkvT[(size_t)(tileN * 128 + row) * 256 + k0 + kc];
        }
        __syncthreads();
        for (int kk = 0; kk < 64; kk += 32) {
            short8 a[4], b[4];
            for (int mi = 0; mi < 4; mi++)
                a[mi] = *(const short8*)&As[wr + mi * 16 + r][kk + q * 8];
            for (int ni = 0; ni < 4; ni++)
                b[ni] = *(const short8*)&Bs[wc + ni * 16 + r][kk + q * 8];
            for (int mi = 0; mi < 4; mi++)
                for (int ni = 0; ni < 4; ni++)
                    acc[mi][ni] = __builtin_amdgcn_mfma_f32_16x16x32_bf16(
                        a[mi], b[ni], acc[mi][ni], 0, 0, 0);
        }
        __syncthreads();
    }
    for (int mi = 0; mi < 4; mi++)
        for (int ni = 0; ni < 4; ni++)
            for (int reg = 0; reg < 4; reg++) {
                int grow = tileM * 128 + wr + mi * 16 + q * 4 + reg;
                int gcol = tileN * 128 + wc + ni * 16 + r;
                float v = acc[mi][ni][reg];
                int which = gcol >> 9, inner = gcol & 511;
                int h = inner >> 6, d = inner & 63;
                int b = grow >> 12, n = grow & 4095;
                size_t off = (((size_t)(b * H_ + h)) * N_ + n) * DH_ + d;
                if (which == 0) Qb[off] = f2bf(v);
                else if (which == 1) Kb[off] = f2bf(v);
                else Vb[off] = f2bf(v);
            }
}

// ---------------- per-head LayerNorm + y init + fragment-layout fp8 t0 ------
__global__ __launch_bounds__(256) void ln_kernel(
    const ushort_t* __restrict__ Vb, const float* __restrict__ gamma,
    const float* __restrict__ beta, const float* __restrict__ coeffs,
    unsigned char* __restrict__ t0T, float* __restrict__ y) {
    int tid = threadIdx.x;
    int wave = tid >> 6, lane = tid & 63;
    size_t row = (size_t)blockIdx.x * 4 + wave;   // bh*4096 + n
    int bh = (int)(row >> 12), n = (int)(row & 4095);
    int h = bh & 7;
    float v = bf2f(Vb[row * 64 + lane]);
    float s = v;
    for (int m = 32; m >= 1; m >>= 1) s += __shfl_xor(s, m, 64);
    float mu = s * (1.f / 64.f);
    float dv = v - mu;
    float s2 = dv * dv;
    for (int m = 32; m >= 1; m >>= 1) s2 += __shfl_xor(s2, m, 64);
    float var = s2 * (1.f / 64.f);
    float vln = dv * rsqrtf(var + 1e-5f) * gamma[lane] + beta[lane];
    float c0 = coeffs[h * 4 + 0];
    y[row * 64 + lane] = c0 * vln;
    // t': fragments (d_blk=lane>>4)*128 + (n>>5), byte (lane&15)*32 + (n&31)
    t0T[(size_t)bh * 262144 +
        ((size_t)(lane >> 4) * 128 + (n >> 5)) * 512 + (lane & 15) * 32 + (n & 31)]
        = f2fp8s(vln);
}

// ---------------- E = exp(Q K^T / 8), fp8, fragment-interleaved layout ------
__global__ __launch_bounds__(256) void s_kernel(
    const ushort_t* __restrict__ Qb, const ushort_t* __restrict__ Kb,
    unsigned char* __restrict__ E, int bh0) {
    __shared__ char smem[36864];
    ushort_t (*As)[PAD] = (ushort_t(*)[PAD])smem;            // Q tile 128x64
    ushort_t (*Bs)[PAD] = (ushort_t(*)[PAD])(smem + 18432);  // K tile 128x64
    unsigned int* E8 = (unsigned int*)smem;                   // 128 x 36 uints
    int bid = blockIdx.x;
    int local = bid >> 10;
    int rem = bid & 1023;
    int ti = rem >> 5, tj = rem & 31;
    int bh = bh0 + local;
    const ushort_t* Q = Qb + (size_t)bh * N_ * 64;
    const ushort_t* K = Kb + (size_t)bh * N_ * 64;
    unsigned char* Eg = E + (size_t)local * N_ * N_;
    int tid = threadIdx.x, w = tid >> 6, lane = tid & 63, q = lane >> 4, r = lane & 15;
    int wj = (w & 1) * 64, wi = (w >> 1) * 64;
    float4v acc[4][4];
    for (int i = 0; i < 4; i++)
        for (int j = 0; j < 4; j++)
            for (int e = 0; e < 4; e++) acc[i][j][e] = 0.f;

    for (int it = 0; it < 4; it++) {
        int idx = tid + it * 256;
        int row = idx >> 3, kc = (idx & 7) * 8;
        *(short8*)&As[row][kc] = *(const short8*)&Q[(size_t)(ti * 128 + row) * 64 + kc];
        *(short8*)&Bs[row][kc] = *(const short8*)&K[(size_t)(tj * 128 + row) * 64 + kc];
    }
    __syncthreads();
    for (int kk = 0; kk < 64; kk += 32) {
        short8 a[4], b[4];
        for (int mi = 0; mi < 4; mi++)             // A = K rows (j direction)
            a[mi] = *(const short8*)&Bs[wj + mi * 16 + r][kk + q * 8];
        for (int ni = 0; ni < 4; ni++)             // B = Q rows (i direction)
            b[ni] = *(const short8*)&As[wi + ni * 16 + r][kk + q * 8];
        for (int mi = 0; mi < 4; mi++)
            for (int ni = 0; ni < 4; ni++)
                acc[mi][ni] = __builtin_amdgcn_mfma_f32_16x16x32_bf16(
                    a[mi], b[ni], acc[mi][ni], 0, 0, 0);
    }
    __syncthreads();   // done with As/Bs; reuse as E8
    for (int mi = 0; mi < 4; mi++)
        for (int ni = 0; ni < 4; ni++) {
            float f0 = __expf(0.125f * acc[mi][ni][0]);
            float f1 = __expf(0.125f * acc[mi][ni][1]);
            float f2 = __expf(0.125f * acc[mi][ni][2]);
            float f3 = __expf(0.125f * acc[mi][ni][3]);
            int p = __builtin_amdgcn_cvt_pk_fp8_f32(f0, f1, 0, false);
            p = __builtin_amdgcn_cvt_pk_fp8_f32(f2, f3, p, true);
            int il = wi + ni * 16 + r;                       // E row i (local)
            int j4 = ((wj + mi * 16) >> 2) + q;              // E col / 4
            E8[il * 36 + j4] = (unsigned int)p;
        }
    __syncthreads();
    // write fragment-interleaved: 32 fragments (8 row_blk x 4 k_blk) x 512B
    for (int it = 0; it < 4; it++) {
        int idx = tid + it * 256;                  // 0..1023
        int f = idx >> 5;                          // fragment 0..31
        int rb = f >> 2, kb = f & 3;
        int o = (idx & 31) * 16;                   // byte offset within fragment
        int il = rb * 16 + (o >> 5);               // local row
        int j4 = kb * 8 + ((o & 31) >> 2);         // local col / 4
        uint4v vv = *(const uint4v*)&E8[il * 36 + j4];
        *(uint4v*)&Eg[((size_t)((ti * 8 + rb) * 128 + (tj * 4 + kb))) * 512 + o] = vv;
    }
}

// ---------------- filter partial: E global-streamed, t shared via LDS -------
// t chunk (4 d_blks x 32 fragments = 64 KB) staged once; K-loop barrier-free:
// E A-fragments from global (512B/wave coalesced), t B-fragments from LDS.
__global__ __launch_bounds__(256) void filter_p2(
    const unsigned char* __restrict__ E, const unsigned char* __restrict__ tinT,
    float* __restrict__ u, float* __restrict__ sbuf, int bh0, int ng) {
    __shared__ unsigned char Ts[4 * 32 * 512];   // 64 KB
    int bid = blockIdx.x;
    int local = bid >> 8;              // 64 ti x SPLIT(4) = 256 blocks per bh
    int rem = bid & 255;
    int ti = rem >> 2;
    int quarter = rem & 3;
    const unsigned char* Eg = E + (size_t)local * N_ * N_;
    const unsigned char* tin = tinT + (size_t)(bh0 + local) * 262144;
    int tid = threadIdx.x, w = tid >> 6, lane = tid & 63, q = lane >> 4, r = lane & 15;
    int off = r * 32 + q * 8;
    int kb0 = quarter * 32;            // starting k_blk (32 frags per quarter)

    // stage t chunk: per d_blk, fragments kb0..kb0+31 are contiguous (16 KB)
    for (int it = 0; it < 16; it++) {
        int idx = tid + it * 256;            // 0..4095 16B chunks
        int db = idx >> 10;                  // d_blk 0..3
        int inner = idx & 1023;              // 16B chunk within 16 KB
        *(uint4v*)&Ts[db * 16384 + inner * 16] =
            *(const uint4v*)&tin[((size_t)(db * 128 + kb0)) * 512 + inner * 16];
    }
    __syncthreads();

    const unsigned char* ep =
        Eg + ((size_t)(ti * 4 + w) * 128 + kb0) * 512 + off;

    float4v acc[4], accs;
    for (int e = 0; e < 4; e++) accs[e] = 0.f;
    for (int j = 0; j < 4; j++)
        for (int e = 0; e < 4; e++) acc[j][e] = 0.f;
    const long bones = 0x3838383838383838L;  // 8x fp8(1.0)

    const int KI = 32;   // fragment-steps in this quarter
#pragma unroll 4
    for (int k = 0; k < KI; k++) {
        long a  = *(const long*)(ep + (size_t)k * 512);
        long b0 = *(const long*)&Ts[k * 512 + off];
        long b1 = *(const long*)&Ts[16384 + k * 512 + off];
        long b2 = *(const long*)&Ts[32768 + k * 512 + off];
        long b3 = *(const long*)&Ts[49152 + k * 512 + off];
        acc[0] = __builtin_amdgcn_mfma_f32_16x16x32_fp8_fp8(a, b0, acc[0], 0, 0, 0);
        acc[1] = __builtin_amdgcn_mfma_f32_16x16x32_fp8_fp8(a, b1, acc[1], 0, 0, 0);
        acc[2] = __builtin_amdgcn_mfma_f32_16x16x32_fp8_fp8(a, b2, acc[2], 0, 0, 0);
        acc[3] = __builtin_amdgcn_mfma_f32_16x16x32_fp8_fp8(a, b3, acc[3], 0, 0, 0);
        accs   = __builtin_amdgcn_mfma_f32_16x16x32_fp8_fp8(a, bones, accs, 0, 0, 0);
    }

    float* ub = u + ((size_t)(quarter * ng + local)) * N_ * 64;
    float* sb = sbuf + ((size_t)(quarter * ng + local)) * N_;
    for (int reg = 0; reg < 4; reg++) {
        int grow = ti * 64 + w * 16 + q * 4 + reg;
        for (int ni = 0; ni < 4; ni++) {
            int gcol = ni * 16 + r;
            ub[(size_t)grow * 64 + gcol] = acc[ni][reg];
        }
        if (r == 0) sb[grow] = accs[reg];
    }
}

// ---------------- normalize: t = Σu/Σs ; y += ck t ; fragment fp8 t out -----
__global__ __launch_bounds__(256) void norm_kernel(
    const float* __restrict__ u, const float* __restrict__ sbuf,
    float* __restrict__ y, unsigned char* __restrict__ toutT,
    const float* __restrict__ coeffs, int bh0, int ng, int kidx, int write_t) {
    int tid = threadIdx.x;
    int wave = tid >> 6, lane = tid & 63;
    size_t idx = (size_t)blockIdx.x * 4 + wave;   // local*4096 + n
    int local = (int)(idx >> 12), n = (int)(idx & 4095);
    int bh = bh0 + local;
    int h = bh & 7;
    float ck = coeffs[h * 4 + kidx];
    float us = 0.f, ss = 0.f;
    for (int sp = 0; sp < SPLIT; sp++) {
        us += u[((size_t)(sp * ng + local) * N_ + n) * 64 + lane];
        ss += sbuf[(size_t)(sp * ng + local) * N_ + n];
    }
    float t = us / ss;
    y[((size_t)bh * N_ + n) * 64 + lane] += ck * t;
    if (write_t)
        toutT[(size_t)bh * 262144 +
              ((size_t)(lane >> 4) * 128 + (n >> 5)) * 512 + (lane & 15) * 32 + (n & 31)]
            = f2fp8s(t);
}

// ---------------- output projection: merged[8192,512] x Wo[512,256] ---------
__global__ __launch_bounds__(256) void out_gemm(
    const float* __restrict__ y, const ushort_t* __restrict__ WoT,
    float* __restrict__ out) {
    __shared__ ushort_t As[128][PAD];
    __shared__ ushort_t Bs[64][PAD];
    int bid = blockIdx.x;
    int tileN = bid & 3, tileM = bid >> 2;
    int tid = threadIdx.x, w = tid >> 6, lane = tid & 63, q = lane >> 4, r = lane & 15;
    int wr = w * 32;
    float4v acc[2][4];
    for (int i = 0; i < 2; i++)
        for (int j = 0; j < 4; j++)
            for (int e = 0; e < 4; e++) acc[i][j][e] = 0.f;

    for (int k0 = 0; k0 < 512; k0 += 64) {
        int h = k0 >> 6;
        for (int it = 0; it < 8; it++) {
            int idx = tid + it * 256;
            int row = idx >> 4, kc = (idx & 15) * 4;
            int grow = tileM * 128 + row;
            int b = grow >> 12, n = grow & 4095;
            const float4* src =
                (const float4*)&y[(((size_t)(b * H_ + h)) * N_ + n) * 64 + kc];
            float4 v = *src;
            ushort4v pv;
            pv[0] = f2bf(v.x); pv[1] = f2bf(v.y); pv[2] = f2bf(v.z); pv[3] = f2bf(v.w);
            *(ushort4v*)&As[row][kc] = pv;
        }
        for (int it = 0; it < 2; it++) {
            int idx = tid + it * 256;
            int row = idx >> 3, kc = (idx & 7) * 8;
            *(short8*)&Bs[row][kc] =
                *(const short8*)&WoT[(size_t)(tileN * 64 + row) * 512 + k0 + kc];
        }
        __syncthreads();
        for (int kk = 0; kk < 64; kk += 32) {
            short8 a[2], b[4];
            a[0] = *(const short8*)&As[wr + r][kk + q * 8];
            a[1] = *(const short8*)&As[wr + 16 + r][kk + q * 8];
            for (int ni = 0; ni < 4; ni++)
                b[ni] = *(const short8*)&Bs[ni * 16 + r][kk + q * 8];
            for (int mi = 0; mi < 2; mi++)
                for (int ni = 0; ni < 4; ni++)
                    acc[mi][ni] = __builtin_amdgcn_mfma_f32_16x16x32_bf16(
                        a[mi], b[ni], acc[mi][ni], 0, 0, 0);
        }
        __syncthreads();
    }
    for (int mi = 0; mi < 2; mi++)
        for (int reg = 0; reg < 4; reg++) {
            int grow = tileM * 128 + wr + mi * 16 + q * 4 + reg;
            for (int ni = 0; ni < 4; ni++) {
                int gcol = tileN * 64 + ni * 16 + r;
                out[(size_t)grow * 256 + gcol] = acc[mi][ni][reg];
            }
        }
}

// ---------------------------------------------------------------------------
extern "C" void kernel_launch(void* const* d_in, const int* in_sizes, int n_in,
                              void* d_out, int out_size, void* d_ws, size_t ws_size,
                              hipStream_t stream) {
    const float* x      = (const float*)d_in[0];
    const float* Wq     = (const float*)d_in[1];
    const float* Wk     = (const float*)d_in[2];
    const float* Wv     = (const float*)d_in[3];
    const float* Wo     = (const float*)d_in[4];
    const float* gamma  = (const float*)d_in[5];
    const float* beta   = (const float*)d_in[6];
    const float* coeffs = (const float*)d_in[7];
    float* out = (float*)d_out;

    char* ws = (char*)d_ws;
    size_t off = 0;
    auto alloc = [&](size_t bytes) -> void* {
        void* p = ws + off;
        off += (bytes + 255) & ~(size_t)255;
        return p;
    };
    ushort_t* xb    = (ushort_t*)alloc((size_t)B_ * N_ * D_ * 2);
    ushort_t* WqkvT = (ushort_t*)alloc((size_t)3 * INNER_ * D_ * 2);
    ushort_t* WoT   = (ushort_t*)alloc((size_t)D_ * INNER_ * 2);
    ushort_t* Qb    = (ushort_t*)alloc((size_t)NBH * N_ * DH_ * 2);
    ushort_t* Kb    = (ushort_t*)alloc((size_t)NBH * N_ * DH_ * 2);
    unsigned char* t0T = (unsigned char*)alloc((size_t)NBH * DH_ * N_);
    unsigned char* t1T = (unsigned char*)alloc((size_t)NBH * DH_ * N_);
    float*    y     = (float*)alloc((size_t)NBH * N_ * DH_ * 4);

    const size_t E1 = (size_t)N_ * N_;  // 16.78 MB per (b,h) in fp8
    int nbh_g = 8;
    while (nbh_g > 1) {
        size_t need = off + (size_t)SPLIT * nbh_g * N_ * DH_ * 4
                      + (size_t)SPLIT * nbh_g * N_ * 4 + 1024
                      + (size_t)nbh_g * E1;
        if (need <= ws_size) break;
        nbh_g >>= 1;
    }
    float* u    = (float*)alloc((size_t)SPLIT * nbh_g * N_ * DH_ * 4);
    float* sbuf = (float*)alloc((size_t)SPLIT * nbh_g * N_ * 4);
    unsigned char* E = (unsigned char*)(ws + off);
    // V (bf16, 8.4 MB) aliased onto the E region: dead once ln_kernel has run,
    // before the first s_kernel write.
    ushort_t* Vb = (ushort_t*)E;

    const int prep_total = B_ * N_ * D_ + 3 * INNER_ * D_ + D_ * INNER_;
    prep_kernel<<<(prep_total + 255) / 256, 256, 0, stream>>>(
        x, Wq, Wk, Wv, Wo, xb, WqkvT, WoT);
    proj_gemm<<<768, 256, 0, stream>>>(xb, WqkvT, Qb, Kb, Vb);
    ln_kernel<<<(NBH * N_) / 4, 256, 0, stream>>>(Vb, gamma, beta, coeffs, t0T, y);

    int fgrid = nbh_g * 64 * SPLIT;
    int ngrid = (nbh_g * N_) / 4;

    for (int bh0 = 0; bh0 < NBH; bh0 += nbh_g) {
        s_kernel<<<nbh_g * 1024, 256, 0, stream>>>(Qb, Kb, E, bh0);
        filter_p2<<<fgrid, 256, 0, stream>>>(E, t0T, u, sbuf, bh0, nbh_g);
        norm_kernel<<<ngrid, 256, 0, stream>>>(u, sbuf, y, t1T, coeffs, bh0, nbh_g, 1, 1);
        filter_p2<<<fgrid, 256, 0, stream>>>(E, t1T, u, sbuf, bh0, nbh_g);
        norm_kernel<<<ngrid, 256, 0, stream>>>(u, sbuf, y, t0T, coeffs, bh0, nbh_g, 2, 1);
        filter_p2<<<fgrid, 256, 0, stream>>>(E, t0T, u, sbuf, bh0, nbh_g);
        norm_kernel<<<ngrid, 256, 0, stream>>>(u, sbuf, y, t1T, coeffs, bh0, nbh_g, 3, 0);
    }
    out_gemm<<<256, 256, 0, stream>>>(y, WoT, out);
}

// Round 11
// 521.561 us; speedup vs baseline: 1.1347x; 1.0010x over previous
//
#include <hip/hip_runtime.h>
#include <stdint.h>

#define B_ 2
#define N_ 4096
#define D_ 256
#define H_ 8
#define DH_ 64
#define INNER_ 512
#define NBH 16
#define PAD 72
#define SPLIT 4

typedef unsigned short ushort_t;
typedef __attribute__((ext_vector_type(8))) short short8;
typedef __attribute__((ext_vector_type(4))) float float4v;
typedef __attribute__((ext_vector_type(4))) unsigned short ushort4v;
typedef __attribute__((ext_vector_type(4))) unsigned int uint4v;

__device__ __forceinline__ ushort_t f2bf(float f) {
    union { float f; unsigned int u; } v; v.f = f;
    unsigned int r = v.u + 0x7FFFu + ((v.u >> 16) & 1u);
    return (ushort_t)(r >> 16);
}
__device__ __forceinline__ float bf2f(ushort_t u) {
    union { unsigned int u; float f; } v; v.u = ((unsigned int)u) << 16;
    return v.f;
}
// full signed fp8 e4m3 encode with subnormal + clamp handling (for t values)
__device__ __forceinline__ unsigned char f2fp8s(float f) {
    union { float f; unsigned int u; } v; v.f = f;
    unsigned int s = (v.u >> 24) & 0x80u;
    v.u &= 0x7FFFFFFFu;
    float a = v.f;
    if (a >= 448.f) return (unsigned char)(s | 0x7E);
    if (a < 0.015625f) {
        int m = (int)(a * 512.f + 0.5f);
        return (unsigned char)(s | (unsigned)m);
    }
    unsigned int u = v.u + 0x7FFFFu + ((v.u >> 20) & 1u);
    return (unsigned char)(s | (((u >> 20) & 0x7FF) - 960));
}

// ---------------- prep: bf16 conversions + weight transposes ----------------
__global__ __launch_bounds__(256) void prep_kernel(
    const float* __restrict__ x, const float* __restrict__ Wq,
    const float* __restrict__ Wk, const float* __restrict__ Wv,
    const float* __restrict__ Wo,
    ushort_t* __restrict__ xb, ushort_t* __restrict__ WqkvT,
    ushort_t* __restrict__ WoT) {
    int idx = blockIdx.x * 256 + threadIdx.x;
    const int total_x = B_ * N_ * D_;
    const int total_wqkv = 3 * INNER_ * D_;
    const int total_wo = D_ * INNER_;
    if (idx < total_x) { xb[idx] = f2bf(x[idx]); return; }
    idx -= total_x;
    if (idx < total_wqkv) {
        int n = idx >> 8, k = idx & 255;
        int which = n >> 9, nn = n & 511;
        const float* W = (which == 0) ? Wq : ((which == 1) ? Wk : Wv);
        WqkvT[idx] = f2bf(W[k * INNER_ + nn]);
        return;
    }
    idx -= total_wqkv;
    if (idx < total_wo) {
        int c = idx >> 9, k = idx & 511;
        WoT[idx] = f2bf(Wo[k * D_ + c]);
    }
}

// ---------------- fused QKV projection GEMM: [8192,256] x [256,1536] --------
__global__ __launch_bounds__(256) void proj_gemm(
    const ushort_t* __restrict__ xb, const ushort_t* __restrict__ WqkvT,
    ushort_t* __restrict__ Qb, ushort_t* __restrict__ Kb,
    ushort_t* __restrict__ Vb) {
    __shared__ ushort_t As[128][PAD];
    __shared__ ushort_t Bs[128][PAD];
    int bid = blockIdx.x;
    int tileN = bid % 12, tileM = bid / 12;
    int tid = threadIdx.x;
    int w = tid >> 6, lane = tid & 63, q = lane >> 4, r = lane & 15;
    int wr = (w & 1) * 64, wc = (w >> 1) * 64;
    float4v acc[4][4];
    for (int i = 0; i < 4; i++)
        for (int j = 0; j < 4; j++)
            for (int e = 0; e < 4; e++) acc[i][j][e] = 0.f;

    for (int k0 = 0; k0 < 256; k0 += 64) {
        for (int it = 0; it < 4; it++) {
            int idx = tid + it * 256;
            int row = idx >> 3, kc = (idx & 7) * 8;
            *(short8*)&As[row][kc] =
                *(const short8*)&xb[(size_t)(tileM * 128 + row) * 256 + k0 + kc];
            *(short8*)&Bs[row][kc] =
                *(const short8*)&WqkvT[(size_t)(tileN * 128 + row) * 256 + k0 + kc];
        }
        __syncthreads();
        for (int kk = 0; kk < 64; kk += 32) {
            short8 a[4], b[4];
            for (int mi = 0; mi < 4; mi++)
                a[mi] = *(const short8*)&As[wr + mi * 16 + r][kk + q * 8];
            for (int ni = 0; ni < 4; ni++)
                b[ni] = *(const short8*)&Bs[wc + ni * 16 + r][kk + q * 8];
            for (int mi = 0; mi < 4; mi++)
                for (int ni = 0; ni < 4; ni++)
                    acc[mi][ni] = __builtin_amdgcn_mfma_f32_16x16x32_bf16(
                        a[mi], b[ni], acc[mi][ni], 0, 0, 0);
        }
        __syncthreads();
    }
    for (int mi = 0; mi < 4; mi++)
        for (int ni = 0; ni < 4; ni++)
            for (int reg = 0; reg < 4; reg++) {
                int grow = tileM * 128 + wr + mi * 16 + q * 4 + reg;
                int gcol = tileN * 128 + wc + ni * 16 + r;
                float v = acc[mi][ni][reg];
                int which = gcol >> 9, inner = gcol & 511;
                int h = inner >> 6, d = inner & 63;
                int b = grow >> 12, n = grow & 4095;
                size_t off = (((size_t)(b * H_ + h)) * N_ + n) * DH_ + d;
                if (which == 0) Qb[off] = f2bf(v);
                else if (which == 1) Kb[off] = f2bf(v);
                else Vb[off] = f2bf(v);
            }
}

// ---------------- per-head LayerNorm + y init + fragment-layout fp8 t0 ------
__global__ __launch_bounds__(256) void ln_kernel(
    const ushort_t* __restrict__ Vb, const float* __restrict__ gamma,
    const float* __restrict__ beta, const float* __restrict__ coeffs,
    unsigned char* __restrict__ t0T, float* __restrict__ y) {
    int tid = threadIdx.x;
    int wave = tid >> 6, lane = tid & 63;
    size_t row = (size_t)blockIdx.x * 4 + wave;   // bh*4096 + n
    int bh = (int)(row >> 12), n = (int)(row & 4095);
    int h = bh & 7;
    float v = bf2f(Vb[row * 64 + lane]);
    float s = v;
    for (int m = 32; m >= 1; m >>= 1) s += __shfl_xor(s, m, 64);
    float mu = s * (1.f / 64.f);
    float dv = v - mu;
    float s2 = dv * dv;
    for (int m = 32; m >= 1; m >>= 1) s2 += __shfl_xor(s2, m, 64);
    float var = s2 * (1.f / 64.f);
    float vln = dv * rsqrtf(var + 1e-5f) * gamma[lane] + beta[lane];
    float c0 = coeffs[h * 4 + 0];
    y[row * 64 + lane] = c0 * vln;
    // t': fragments (d_blk=lane>>4)*128 + (n>>5), byte (lane&15)*32 + (n&31)
    t0T[(size_t)bh * 262144 +
        ((size_t)(lane >> 4) * 128 + (n >> 5)) * 512 + (lane & 15) * 32 + (n & 31)]
        = f2fp8s(vln);
}

// ---------------- E = exp(Q K^T / 8), fp8, direct fragment stores -----------
__global__ __launch_bounds__(256) void s_kernel(
    const ushort_t* __restrict__ Qb, const ushort_t* __restrict__ Kb,
    unsigned char* __restrict__ E, int bh0) {
    __shared__ ushort_t As[128][PAD];   // Q tile 128x64
    __shared__ ushort_t Bs[128][PAD];   // K tile 128x64
    int bid = blockIdx.x;
    int local = bid >> 10;
    int rem = bid & 1023;
    int ti = rem >> 5, tj = rem & 31;
    int bh = bh0 + local;
    const ushort_t* Q = Qb + (size_t)bh * N_ * 64;
    const ushort_t* K = Kb + (size_t)bh * N_ * 64;
    unsigned char* Eg = E + (size_t)local * N_ * N_;
    int tid = threadIdx.x, w = tid >> 6, lane = tid & 63, q = lane >> 4, r = lane & 15;
    int wj = (w & 1) * 64, wi = (w >> 1) * 64;
    float4v acc[4][4];
    for (int i = 0; i < 4; i++)
        for (int j = 0; j < 4; j++)
            for (int e = 0; e < 4; e++) acc[i][j][e] = 0.f;

    for (int it = 0; it < 4; it++) {
        int idx = tid + it * 256;
        int row = idx >> 3, kc = (idx & 7) * 8;
        *(short8*)&As[row][kc] = *(const short8*)&Q[(size_t)(ti * 128 + row) * 64 + kc];
        *(short8*)&Bs[row][kc] = *(const short8*)&K[(size_t)(tj * 128 + row) * 64 + kc];
    }
    __syncthreads();
    for (int kk = 0; kk < 64; kk += 32) {
        short8 a[4], b[4];
        for (int mi = 0; mi < 4; mi++)             // A = K rows (j direction)
            a[mi] = *(const short8*)&Bs[wj + mi * 16 + r][kk + q * 8];
        for (int ni = 0; ni < 4; ni++)             // B = Q rows (i direction)
            b[ni] = *(const short8*)&As[wi + ni * 16 + r][kk + q * 8];
        for (int mi = 0; mi < 4; mi++)
            for (int ni = 0; ni < 4; ni++)
                acc[mi][ni] = __builtin_amdgcn_mfma_f32_16x16x32_bf16(
                    a[mi], b[ni], acc[mi][ni], 0, 0, 0);
    }
    // direct fragment-interleaved store: lane (q,r) of acc[mi][ni] holds
    // E[i = wi+ni*16+r][j = wj+mi*16+q*4 .. +3] -> one packed dword.
    for (int mi = 0; mi < 4; mi++)
        for (int ni = 0; ni < 4; ni++) {
            float f0 = __expf(0.125f * acc[mi][ni][0]);
            float f1 = __expf(0.125f * acc[mi][ni][1]);
            float f2 = __expf(0.125f * acc[mi][ni][2]);
            float f3 = __expf(0.125f * acc[mi][ni][3]);
            int p = __builtin_amdgcn_cvt_pk_fp8_f32(f0, f1, 0, false);
            p = __builtin_amdgcn_cvt_pk_fp8_f32(f2, f3, p, true);
            int rb = ti * 8 + (w >> 1) * 4 + ni;             // row fragment
            int cb = tj * 4 + (w & 1) * 2 + (mi >> 1);       // col fragment
            *(unsigned int*)&Eg[((size_t)rb * 128 + cb) * 512 +
                                r * 32 + (mi & 1) * 16 + q * 4] = (unsigned int)p;
        }
}

// ---------------- filter partial: M=128, E global-streamed, t in LDS --------
// t chunk (4 d_blks x 32 fragments = 64 KB) staged once; K-loop barrier-free:
// each wave streams 2 E row-fragments from global, t B-fragments from LDS.
__global__ __launch_bounds__(256) void filter_p2(
    const unsigned char* __restrict__ E, const unsigned char* __restrict__ tinT,
    float* __restrict__ u, float* __restrict__ sbuf, int bh0, int ng) {
    __shared__ unsigned char Ts[4 * 32 * 512];   // 64 KB
    int bid = blockIdx.x;
    int local = bid >> 7;              // 32 ti x SPLIT(4) = 128 blocks per bh
    int rem = bid & 127;
    int ti = rem >> 2;                 // 128-row tile, 0..31
    int quarter = rem & 3;
    const unsigned char* Eg = E + (size_t)local * N_ * N_;
    const unsigned char* tin = tinT + (size_t)(bh0 + local) * 262144;
    int tid = threadIdx.x, w = tid >> 6, lane = tid & 63, q = lane >> 4, r = lane & 15;
    int off = r * 32 + q * 8;
    int kb0 = quarter * 32;            // starting k_blk (32 frags per quarter)

    // stage t chunk: per d_blk, fragments kb0..kb0+31 are contiguous (16 KB)
    for (int it = 0; it < 16; it++) {
        int idx = tid + it * 256;            // 0..4095 16B chunks
        int db = idx >> 10;                  // d_blk 0..3
        int inner = idx & 1023;              // 16B chunk within 16 KB
        *(uint4v*)&Ts[db * 16384 + inner * 16] =
            *(const uint4v*)&tin[((size_t)(db * 128 + kb0)) * 512 + inner * 16];
    }
    __syncthreads();

    const unsigned char* ep0 =
        Eg + ((size_t)(ti * 8 + w) * 128 + kb0) * 512 + off;
    const unsigned char* ep1 =
        Eg + ((size_t)(ti * 8 + 4 + w) * 128 + kb0) * 512 + off;

    float4v acc[2][4], accs[2];
    for (int mi = 0; mi < 2; mi++) {
        for (int e = 0; e < 4; e++) accs[mi][e] = 0.f;
        for (int j = 0; j < 4; j++)
            for (int e = 0; e < 4; e++) acc[mi][j][e] = 0.f;
    }
    const long bones = 0x3838383838383838L;  // 8x fp8(1.0)

    const int KI = 32;   // fragment-steps in this quarter
#pragma unroll 4
    for (int k = 0; k < KI; k++) {
        long a0 = *(const long*)(ep0 + (size_t)k * 512);
        long a1 = *(const long*)(ep1 + (size_t)k * 512);
        long b0 = *(const long*)&Ts[k * 512 + off];
        long b1 = *(const long*)&Ts[16384 + k * 512 + off];
        long b2 = *(const long*)&Ts[32768 + k * 512 + off];
        long b3 = *(const long*)&Ts[49152 + k * 512 + off];
        acc[0][0] = __builtin_amdgcn_mfma_f32_16x16x32_fp8_fp8(a0, b0, acc[0][0], 0, 0, 0);
        acc[0][1] = __builtin_amdgcn_mfma_f32_16x16x32_fp8_fp8(a0, b1, acc[0][1], 0, 0, 0);
        acc[0][2] = __builtin_amdgcn_mfma_f32_16x16x32_fp8_fp8(a0, b2, acc[0][2], 0, 0, 0);
        acc[0][3] = __builtin_amdgcn_mfma_f32_16x16x32_fp8_fp8(a0, b3, acc[0][3], 0, 0, 0);
        accs[0]   = __builtin_amdgcn_mfma_f32_16x16x32_fp8_fp8(a0, bones, accs[0], 0, 0, 0);
        acc[1][0] = __builtin_amdgcn_mfma_f32_16x16x32_fp8_fp8(a1, b0, acc[1][0], 0, 0, 0);
        acc[1][1] = __builtin_amdgcn_mfma_f32_16x16x32_fp8_fp8(a1, b1, acc[1][1], 0, 0, 0);
        acc[1][2] = __builtin_amdgcn_mfma_f32_16x16x32_fp8_fp8(a1, b2, acc[1][2], 0, 0, 0);
        acc[1][3] = __builtin_amdgcn_mfma_f32_16x16x32_fp8_fp8(a1, b3, acc[1][3], 0, 0, 0);
        accs[1]   = __builtin_amdgcn_mfma_f32_16x16x32_fp8_fp8(a1, bones, accs[1], 0, 0, 0);
    }

    float* ub = u + ((size_t)(quarter * ng + local)) * N_ * 64;
    float* sb = sbuf + ((size_t)(quarter * ng + local)) * N_;
    for (int mi = 0; mi < 2; mi++)
        for (int reg = 0; reg < 4; reg++) {
            int grow = (ti * 8 + mi * 4 + w) * 16 + q * 4 + reg;
            for (int ni = 0; ni < 4; ni++) {
                int gcol = ni * 16 + r;
                ub[(size_t)grow * 64 + gcol] = acc[mi][ni][reg];
            }
            if (r == 0) sb[grow] = accs[mi][reg];
        }
}

// ---------------- normalize: t = Σu/Σs ; y += ck t ; fragment fp8 t out -----
__global__ __launch_bounds__(256) void norm_kernel(
    const float* __restrict__ u, const float* __restrict__ sbuf,
    float* __restrict__ y, unsigned char* __restrict__ toutT,
    const float* __restrict__ coeffs, int bh0, int ng, int kidx, int write_t) {
    int tid = threadIdx.x;
    int wave = tid >> 6, lane = tid & 63;
    size_t idx = (size_t)blockIdx.x * 4 + wave;   // local*4096 + n
    int local = (int)(idx >> 12), n = (int)(idx & 4095);
    int bh = bh0 + local;
    int h = bh & 7;
    float ck = coeffs[h * 4 + kidx];
    float us = 0.f, ss = 0.f;
    for (int sp = 0; sp < SPLIT; sp++) {
        us += u[((size_t)(sp * ng + local) * N_ + n) * 64 + lane];
        ss += sbuf[(size_t)(sp * ng + local) * N_ + n];
    }
    float t = us / ss;
    y[((size_t)bh * N_ + n) * 64 + lane] += ck * t;
    if (write_t)
        toutT[(size_t)bh * 262144 +
              ((size_t)(lane >> 4) * 128 + (n >> 5)) * 512 + (lane & 15) * 32 + (n & 31)]
            = f2fp8s(t);
}

// ---------------- output projection: merged[8192,512] x Wo[512,256] ---------
__global__ __launch_bounds__(256) void out_gemm(
    const float* __restrict__ y, const ushort_t* __restrict__ WoT,
    float* __restrict__ out) {
    __shared__ ushort_t As[128][PAD];
    __shared__ ushort_t Bs[64][PAD];
    int bid = blockIdx.x;
    int tileN = bid & 3, tileM = bid >> 2;
    int tid = threadIdx.x, w = tid >> 6, lane = tid & 63, q = lane >> 4, r = lane & 15;
    int wr = w * 32;
    float4v acc[2][4];
    for (int i = 0; i < 2; i++)
        for (int j = 0; j < 4; j++)
            for (int e = 0; e < 4; e++) acc[i][j][e] = 0.f;

    for (int k0 = 0; k0 < 512; k0 += 64) {
        int h = k0 >> 6;
        for (int it = 0; it < 8; it++) {
            int idx = tid + it * 256;
            int row = idx >> 4, kc = (idx & 15) * 4;
            int grow = tileM * 128 + row;
            int b = grow >> 12, n = grow & 4095;
            const float4* src =
                (const float4*)&y[(((size_t)(b * H_ + h)) * N_ + n) * 64 + kc];
            float4 v = *src;
            ushort4v pv;
            pv[0] = f2bf(v.x); pv[1] = f2bf(v.y); pv[2] = f2bf(v.z); pv[3] = f2bf(v.w);
            *(ushort4v*)&As[row][kc] = pv;
        }
        for (int it = 0; it < 2; it++) {
            int idx = tid + it * 256;
            int row = idx >> 3, kc = (idx & 7) * 8;
            *(short8*)&Bs[row][kc] =
                *(const short8*)&WoT[(size_t)(tileN * 64 + row) * 512 + k0 + kc];
        }
        __syncthreads();
        for (int kk = 0; kk < 64; kk += 32) {
            short8 a[2], b[4];
            a[0] = *(const short8*)&As[wr + r][kk + q * 8];
            a[1] = *(const short8*)&As[wr + 16 + r][kk + q * 8];
            for (int ni = 0; ni < 4; ni++)
                b[ni] = *(const short8*)&Bs[ni * 16 + r][kk + q * 8];
            for (int mi = 0; mi < 2; mi++)
                for (int ni = 0; ni < 4; ni++)
                    acc[mi][ni] = __builtin_amdgcn_mfma_f32_16x16x32_bf16(
                        a[mi], b[ni], acc[mi][ni], 0, 0, 0);
        }
        __syncthreads();
    }
    for (int mi = 0; mi < 2; mi++)
        for (int reg = 0; reg < 4; reg++) {
            int grow = tileM * 128 + wr + mi * 16 + q * 4 + reg;
            for (int ni = 0; ni < 4; ni++) {
                int gcol = tileN * 64 + ni * 16 + r;
                out[(size_t)grow * 256 + gcol] = acc[mi][ni][reg];
            }
        }
}

// ---------------------------------------------------------------------------
extern "C" void kernel_launch(void* const* d_in, const int* in_sizes, int n_in,
                              void* d_out, int out_size, void* d_ws, size_t ws_size,
                              hipStream_t stream) {
    const float* x      = (const float*)d_in[0];
    const float* Wq     = (const float*)d_in[1];
    const float* Wk     = (const float*)d_in[2];
    const float* Wv     = (const float*)d_in[3];
    const float* Wo     = (const float*)d_in[4];
    const float* gamma  = (const float*)d_in[5];
    const float* beta   = (const float*)d_in[6];
    const float* coeffs = (const float*)d_in[7];
    float* out = (float*)d_out;

    char* ws = (char*)d_ws;
    size_t off = 0;
    auto alloc = [&](size_t bytes) -> void* {
        void* p = ws + off;
        off += (bytes + 255) & ~(size_t)255;
        return p;
    };
    ushort_t* xb    = (ushort_t*)alloc((size_t)B_ * N_ * D_ * 2);
    ushort_t* WqkvT = (ushort_t*)alloc((size_t)3 * INNER_ * D_ * 2);
    ushort_t* WoT   = (ushort_t*)alloc((size_t)D_ * INNER_ * 2);
    ushort_t* Qb    = (ushort_t*)alloc((size_t)NBH * N_ * DH_ * 2);
    ushort_t* Kb    = (ushort_t*)alloc((size_t)NBH * N_ * DH_ * 2);
    unsigned char* t0T = (unsigned char*)alloc((size_t)NBH * DH_ * N_);
    unsigned char* t1T = (unsigned char*)alloc((size_t)NBH * DH_ * N_);
    float*    y     = (float*)alloc((size_t)NBH * N_ * DH_ * 4);

    const size_t E1 = (size_t)N_ * N_;  // 16.78 MB per (b,h) in fp8
    int nbh_g = 8;
    while (nbh_g > 1) {
        size_t need = off + (size_t)SPLIT * nbh_g * N_ * DH_ * 4
                      + (size_t)SPLIT * nbh_g * N_ * 4 + 1024
                      + (size_t)nbh_g * E1;
        if (need <= ws_size) break;
        nbh_g >>= 1;
    }
    float* u    = (float*)alloc((size_t)SPLIT * nbh_g * N_ * DH_ * 4);
    float* sbuf = (float*)alloc((size_t)SPLIT * nbh_g * N_ * 4);
    unsigned char* E = (unsigned char*)(ws + off);
    // V (bf16, 8.4 MB) aliased onto the E region: dead once ln_kernel has run,
    // before the first s_kernel write.
    ushort_t* Vb = (ushort_t*)E;

    const int prep_total = B_ * N_ * D_ + 3 * INNER_ * D_ + D_ * INNER_;
    prep_kernel<<<(prep_total + 255) / 256, 256, 0, stream>>>(
        x, Wq, Wk, Wv, Wo, xb, WqkvT, WoT);
    proj_gemm<<<768, 256, 0, stream>>>(xb, WqkvT, Qb, Kb, Vb);
    ln_kernel<<<(NBH * N_) / 4, 256, 0, stream>>>(Vb, gamma, beta, coeffs, t0T, y);

    int fgrid = nbh_g * 32 * SPLIT;
    int ngrid = (nbh_g * N_) / 4;

    for (int bh0 = 0; bh0 < NBH; bh0 += nbh_g) {
        s_kernel<<<nbh_g * 1024, 256, 0, stream>>>(Qb, Kb, E, bh0);
        filter_p2<<<fgrid, 256, 0, stream>>>(E, t0T, u, sbuf, bh0, nbh_g);
        norm_kernel<<<ngrid, 256, 0, stream>>>(u, sbuf, y, t1T, coeffs, bh0, nbh_g, 1, 1);
        filter_p2<<<fgrid, 256, 0, stream>>>(E, t1T, u, sbuf, bh0, nbh_g);
        norm_kernel<<<ngrid, 256, 0, stream>>>(u, sbuf, y, t0T, coeffs, bh0, nbh_g, 2, 1);
        filter_p2<<<fgrid, 256, 0, stream>>>(E, t0T, u, sbuf, bh0, nbh_g);
        norm_kernel<<<ngrid, 256, 0, stream>>>(u, sbuf, y, t1T, coeffs, bh0, nbh_g, 3, 0);
    }
    out_gemm<<<256, 256, 0, stream>>>(y, WoT, out);
}